// Round 8
// baseline (2885.142 us; speedup 1.0000x reference)
//
#include <hip/hip_runtime.h>

#define N_NODES    100000
#define N_EDGES    1600000
#define D_EMB      128
#define ROUNDS     4
#define M_OUT      32
#define NUM_GRAPHS 512

#define N_TILES    (N_NODES / 32)        // 3125 GEMM tiles
#define GEMM_BLOCKS 1024

#define NCHUNK     8
#define CHUNK_N    12500                 // dst nodes per chunk
#define CHUNK_CAP  210000                // >24 sigma above E[200000]
#define FILLD_BLOCKS 1024
#define HISTD_BLOCKS 1024

#define SCAN_ELEMS_PER_BLOCK 1024
#define SCAN_NBLK ((N_NODES + SCAN_ELEMS_PER_BLOCK - 1) / SCAN_ELEMS_PER_BLOCK)  // 98

typedef __attribute__((ext_vector_type(8))) short short8;
typedef __attribute__((ext_vector_type(4))) float f32x4;

static __device__ __forceinline__ unsigned short f2bf(float f) {
    union { float f; unsigned u; } v; v.f = f;
    unsigned u = v.u;
    unsigned r = (u + 0x7FFFu + ((u >> 16) & 1u)) >> 16;   // RNE
    return (unsigned short)r;
}
static __device__ __forceinline__ float bf2f(unsigned short h) {
    union { unsigned u; float f; } v; v.u = ((unsigned)h) << 16;
    return v.f;
}

// ---------------------------------------------------------------------------
// Weight prep: WTall[mi][n][k] = bf16( W_mi[k][n] )
// ---------------------------------------------------------------------------
__global__ __launch_bounds__(256) void prep_weights_kernel(
    const float* __restrict__ emb_W, const float* __restrict__ msg_W,
    const float* __restrict__ upd_W, unsigned short* __restrict__ WTall)
{
    const int mi = blockIdx.x;
    const float* W = (mi == 0) ? emb_W
                   : (mi <= 4) ? msg_W + (size_t)(mi - 1) * D_EMB * D_EMB
                               : upd_W + (size_t)(mi - 5) * D_EMB * D_EMB;
    unsigned short* WT = WTall + (size_t)mi * D_EMB * D_EMB;
    for (int idx = threadIdx.x; idx < D_EMB * D_EMB; idx += 256) {
        const int n = idx >> 7, k = idx & 127;
        WT[idx] = f2bf(W[k * D_EMB + n]);
    }
}

// ---------------------------------------------------------------------------
// Looped bf16 MFMA GEMM (emb + msg rounds). Double-buffered A staging,
// B fragments loaded once per block.
// MODE 0: outb = bf16(relu(AW+b))     (msg)
// MODE 2: state = bf16(relu(AW+b))    (embed, A is fp32 x)
// ---------------------------------------------------------------------------
template<int MODE, bool AF32>
__global__ __launch_bounds__(256) void gemm_loop_kernel(
    const void* __restrict__ Aptr, const unsigned short* __restrict__ WT,
    const float* __restrict__ bias, unsigned short* __restrict__ state,
    unsigned short* __restrict__ outb)
{
    __shared__ unsigned short As[2][32][136];   // +8 pad: row stride 272 B

    const int tid  = threadIdx.x;
    const int lane = tid & 63;
    const int w    = tid >> 6;
    const int m    = lane & 15;
    const int g    = lane >> 4;

    short8 bfr[2][4];
    #pragma unroll
    for (int ct = 0; ct < 2; ++ct) {
        const int n = w * 32 + ct * 16 + m;
        #pragma unroll
        for (int ks = 0; ks < 4; ++ks)
            bfr[ct][ks] = *(const short8*)&WT[n * D_EMB + ks * 32 + g * 8];
    }
    const float bv0 = bias[w * 32 + m];
    const float bv1 = bias[w * 32 + 16 + m];

    int tile = blockIdx.x;

    if (AF32) {
        const float4* A4 = (const float4*)Aptr;
        #pragma unroll
        for (int i = 0; i < 4; ++i) {
            const int ch = tid + (i << 8);
            const float4 f = A4[(size_t)tile * 1024 + ch];
            ushort4 h; h.x = f2bf(f.x); h.y = f2bf(f.y); h.z = f2bf(f.z); h.w = f2bf(f.w);
            *(ushort4*)&As[0][ch >> 5][(ch & 31) << 2] = h;
        }
    } else {
        const uint4* A2 = (const uint4*)Aptr;
        #pragma unroll
        for (int i = 0; i < 2; ++i) {
            const int ch = tid + (i << 8);
            const uint4 v = A2[(size_t)tile * 512 + ch];
            *(uint4*)&As[0][ch >> 4][(ch & 15) << 3] = v;
        }
    }
    __syncthreads();

    int cur = 0;
    while (true) {
        const int next = tile + GEMM_BLOCKS;
        const bool have = next < N_TILES;

        float4 rgf[4]; uint4 rgu[2];
        if (have) {
            if (AF32) {
                const float4* A4 = (const float4*)Aptr;
                #pragma unroll
                for (int i = 0; i < 4; ++i)
                    rgf[i] = A4[(size_t)next * 1024 + tid + (i << 8)];
            } else {
                const uint4* A2 = (const uint4*)Aptr;
                #pragma unroll
                for (int i = 0; i < 2; ++i)
                    rgu[i] = A2[(size_t)next * 512 + tid + (i << 8)];
            }
        }

        short8 a[2][4];
        #pragma unroll
        for (int rt = 0; rt < 2; ++rt)
            #pragma unroll
            for (int ks = 0; ks < 4; ++ks)
                a[rt][ks] = *(const short8*)&As[cur][rt * 16 + m][ks * 32 + g * 8];

        f32x4 acc[2][2] = {};
        #pragma unroll
        for (int ks = 0; ks < 4; ++ks)
            #pragma unroll
            for (int rt = 0; rt < 2; ++rt)
                #pragma unroll
                for (int ct = 0; ct < 2; ++ct)
                    acc[rt][ct] = __builtin_amdgcn_mfma_f32_16x16x32_bf16(
                        a[rt][ks], bfr[ct][ks], acc[rt][ct], 0, 0, 0);

        if (have) {
            if (AF32) {
                #pragma unroll
                for (int i = 0; i < 4; ++i) {
                    const int ch = tid + (i << 8);
                    ushort4 h;
                    h.x = f2bf(rgf[i].x); h.y = f2bf(rgf[i].y);
                    h.z = f2bf(rgf[i].z); h.w = f2bf(rgf[i].w);
                    *(ushort4*)&As[cur ^ 1][ch >> 5][(ch & 31) << 2] = h;
                }
            } else {
                #pragma unroll
                for (int i = 0; i < 2; ++i) {
                    const int ch = tid + (i << 8);
                    *(uint4*)&As[cur ^ 1][ch >> 4][(ch & 15) << 3] = rgu[i];
                }
            }
        }

        #pragma unroll
        for (int rt = 0; rt < 2; ++rt) {
            #pragma unroll
            for (int ct = 0; ct < 2; ++ct) {
                const int col = w * 32 + ct * 16 + m;
                const float bv = ct ? bv1 : bv0;
                #pragma unroll
                for (int r = 0; r < 4; ++r) {
                    const int row = tile * 32 + rt * 16 + g * 4 + r;
                    const size_t idx = (size_t)row * D_EMB + col;
                    const float v = fmaxf(acc[rt][ct][r] + bv, 0.f);
                    if (MODE == 0) outb[idx] = f2bf(v);
                    else           state[idx] = f2bf(v);
                }
            }
        }

        if (!have) break;
        __syncthreads();
        cur ^= 1;
        tile = next;
    }
}

// ---------------------------------------------------------------------------
// Build pass A (XCD-confined multipass dense append): block b handles only
// chunk c=b&7 (round-robin block->XCD mapping => chunk c's buffer lines are
// written from XCD c only and fill sequentially -> one full-line writeback).
// Per-wave ballot count, one global atomic per wave.
// Entry pack: (src << 14) | (d - c*CHUNK_N)
// ---------------------------------------------------------------------------
__global__ __launch_bounds__(256) void partition_mp_kernel(
    const int* __restrict__ src, const int* __restrict__ dst,
    int* __restrict__ chunkCnt, unsigned* __restrict__ chunkbuf)
{
    const int tid = threadIdx.x;
    const int c = blockIdx.x & 7;
    const int e = (blockIdx.x >> 3) * 256 + tid;
    const int d = dst[e];
    const bool match = (unsigned)(d - c * CHUNK_N) < (unsigned)CHUNK_N;

    const unsigned long long mask = __ballot(match);
    const int lane = tid & 63;
    const int myoff = __popcll(mask & ((1ull << lane) - 1ull));
    const int wcnt = __popcll(mask);

    int wb = 0;
    if (lane == 0 && wcnt) wb = atomicAdd(&chunkCnt[c], wcnt);
    wb = __shfl(wb, 0, 64);

    if (match)
        chunkbuf[(size_t)c * CHUNK_CAP + wb + myoff] =
            ((unsigned)src[e] << 14) | (unsigned)(d - c * CHUNK_N);
}

// ---------------------------------------------------------------------------
// Build pass B: XCD-confined per-node degree from chunkbuf. Block b handles
// chunk b&7 -> deg slice (50 KB) stays in that XCD's L2, no line bouncing.
// ---------------------------------------------------------------------------
__global__ __launch_bounds__(256) void histD_kernel(
    const unsigned* __restrict__ chunkbuf, const int* __restrict__ chunkCnt,
    int* __restrict__ deg)
{
    const int c = blockIdx.x & 7;
    const int cnt = chunkCnt[c];
    const unsigned* buf = chunkbuf + (size_t)c * CHUNK_CAP;
    const int stride = (HISTD_BLOCKS / 8) * 256;
    for (int i = (blockIdx.x >> 3) * 256 + threadIdx.x; i < cnt; i += stride)
        atomicAdd(&deg[c * CHUNK_N + (int)(buf[i] & 0x3fffu)], 1);
}

// ---------------------------------------------------------------------------
// Per-node exclusive scan (3 kernels)
// ---------------------------------------------------------------------------
__global__ __launch_bounds__(256) void scan_local_kernel(
    const int* __restrict__ deg, int* __restrict__ rp, int* __restrict__ partials)
{
    __shared__ int sm[256];
    const int tid  = threadIdx.x;
    const int base = blockIdx.x * SCAN_ELEMS_PER_BLOCK + tid * 4;

    int v0 = (base + 0 < N_NODES) ? deg[base + 0] : 0;
    int v1 = (base + 1 < N_NODES) ? deg[base + 1] : 0;
    int v2 = (base + 2 < N_NODES) ? deg[base + 2] : 0;
    int v3 = (base + 3 < N_NODES) ? deg[base + 3] : 0;
    const int tot = v0 + v1 + v2 + v3;

    sm[tid] = tot;
    __syncthreads();
    #pragma unroll
    for (int off = 1; off < 256; off <<= 1) {
        const int x = (tid >= off) ? sm[tid - off] : 0;
        __syncthreads();
        sm[tid] += x;
        __syncthreads();
    }
    const int bex = sm[tid] - tot;

    if (base + 0 < N_NODES) rp[base + 0] = bex;
    if (base + 1 < N_NODES) rp[base + 1] = bex + v0;
    if (base + 2 < N_NODES) rp[base + 2] = bex + v0 + v1;
    if (base + 3 < N_NODES) rp[base + 3] = bex + v0 + v1 + v2;
    if (tid == 255) partials[blockIdx.x] = sm[255];
}

__global__ __launch_bounds__(128) void scan_partials_kernel(int* __restrict__ partials)
{
    __shared__ int sm[128];
    const int tid = threadIdx.x;
    const int v = (tid < SCAN_NBLK) ? partials[tid] : 0;
    sm[tid] = v;
    __syncthreads();
    #pragma unroll
    for (int off = 1; off < 128; off <<= 1) {
        const int x = (tid >= off) ? sm[tid - off] : 0;
        __syncthreads();
        sm[tid] += x;
        __syncthreads();
    }
    if (tid < SCAN_NBLK) partials[tid] = sm[tid] - v;
}

__global__ __launch_bounds__(256) void scan_fixup_kernel(
    int* __restrict__ rp, const int* __restrict__ partials, int* __restrict__ pos)
{
    const int i = blockIdx.x * 256 + threadIdx.x;
    if (i < N_NODES) {
        const int v = rp[i] + partials[i >> 10];
        rp[i] = v;
        pos[i] = v;
    }
    if (i == 0) rp[N_NODES] = N_EDGES;
}

// ---------------------------------------------------------------------------
// Build pass D: XCD-confined fine fill (chunk slice + esrc slice + pos slice
// fit one XCD L2).
// ---------------------------------------------------------------------------
__global__ __launch_bounds__(256) void fillD_kernel(
    const unsigned* __restrict__ chunkbuf, const int* __restrict__ chunkCnt,
    int* __restrict__ pos, int* __restrict__ esrc)
{
    const int c = blockIdx.x & 7;
    const int cnt = chunkCnt[c];
    const unsigned* buf = chunkbuf + (size_t)c * CHUNK_CAP;
    const int stride = (FILLD_BLOCKS / 8) * 256;
    for (int i = (blockIdx.x >> 3) * 256 + threadIdx.x; i < cnt; i += stride) {
        const unsigned ev = buf[i];
        const int d = c * CHUNK_N + (int)(ev & 0x3fffu);
        const int q = atomicAdd(&pos[d], 1);
        esrc[q] = (int)(ev >> 14);
    }
}

// ---------------------------------------------------------------------------
// Fused gather + update-GEMM. Block b owns dst nodes [32b, 32b+32).
// Gather: 16 slots x 16 lanes, DYNAMIC work queue over the 32 nodes (LDS
// counter pop) for load balance; fp32 register accumulation, 4 edges in
// flight; one ds_write_b128 per (node) row chunk. Then MFMA + residual.
// ---------------------------------------------------------------------------
__global__ __launch_bounds__(256) void fused_upd_kernel(
    const unsigned short* __restrict__ msg, const int* __restrict__ rp,
    const int* __restrict__ esrc, const unsigned short* __restrict__ WT,
    const float* __restrict__ bias, unsigned short* __restrict__ state)
{
    __shared__ unsigned short As[32][136];    // 8.5 KB, +8 pad
    __shared__ int wq;

    const int tid  = threadIdx.x;
    const int lane = tid & 63;
    const int wid  = tid >> 6;
    const int m    = lane & 15;
    const int g    = lane >> 4;
    const int b    = blockIdx.x;
    const int j    = tid & 15;       // 16B column chunk within row

    if (tid == 0) wq = 0;

    short8 bfr[2][4];
    #pragma unroll
    for (int ct = 0; ct < 2; ++ct) {
        const int n = wid * 32 + ct * 16 + m;
        #pragma unroll
        for (int ks = 0; ks < 4; ++ks)
            bfr[ct][ks] = *(const short8*)&WT[n * D_EMB + ks * 32 + g * 8];
    }
    const float bv0 = bias[wid * 32 + m];
    const float bv1 = bias[wid * 32 + 16 + m];

    __syncthreads();   // wq ready

    const uint4* m4 = (const uint4*)msg;   // row = 16 uint4

    while (true) {
        int t = 0;
        if (j == 0) t = atomicAdd(&wq, 1);
        t = __shfl(t, lane & 48, 64);      // broadcast from 16-group leader
        if (t >= 32) break;

        const int n = b * 32 + t;
        const int beg = rp[n];
        const int end = rp[n + 1];

        float a0[8] = {0,0,0,0,0,0,0,0};
        float a1[8] = {0,0,0,0,0,0,0,0};
        int i = beg;
        for (; i + 3 < end; i += 4) {
            const uint4 v0 = m4[(size_t)esrc[i]     * 16 + j];
            const uint4 v1 = m4[(size_t)esrc[i + 1] * 16 + j];
            const uint4 v2 = m4[(size_t)esrc[i + 2] * 16 + j];
            const uint4 v3 = m4[(size_t)esrc[i + 3] * 16 + j];
            a0[0] += bf2f(v0.x & 0xffff); a0[1] += bf2f(v0.x >> 16);
            a0[2] += bf2f(v0.y & 0xffff); a0[3] += bf2f(v0.y >> 16);
            a0[4] += bf2f(v0.z & 0xffff); a0[5] += bf2f(v0.z >> 16);
            a0[6] += bf2f(v0.w & 0xffff); a0[7] += bf2f(v0.w >> 16);
            a1[0] += bf2f(v1.x & 0xffff); a1[1] += bf2f(v1.x >> 16);
            a1[2] += bf2f(v1.y & 0xffff); a1[3] += bf2f(v1.y >> 16);
            a1[4] += bf2f(v1.z & 0xffff); a1[5] += bf2f(v1.z >> 16);
            a1[6] += bf2f(v1.w & 0xffff); a1[7] += bf2f(v1.w >> 16);
            a0[0] += bf2f(v2.x & 0xffff); a0[1] += bf2f(v2.x >> 16);
            a0[2] += bf2f(v2.y & 0xffff); a0[3] += bf2f(v2.y >> 16);
            a0[4] += bf2f(v2.z & 0xffff); a0[5] += bf2f(v2.z >> 16);
            a0[6] += bf2f(v2.w & 0xffff); a0[7] += bf2f(v2.w >> 16);
            a1[0] += bf2f(v3.x & 0xffff); a1[1] += bf2f(v3.x >> 16);
            a1[2] += bf2f(v3.y & 0xffff); a1[3] += bf2f(v3.y >> 16);
            a1[4] += bf2f(v3.z & 0xffff); a1[5] += bf2f(v3.z >> 16);
            a1[6] += bf2f(v3.w & 0xffff); a1[7] += bf2f(v3.w >> 16);
        }
        for (; i < end; ++i) {
            const uint4 v0 = m4[(size_t)esrc[i] * 16 + j];
            a0[0] += bf2f(v0.x & 0xffff); a0[1] += bf2f(v0.x >> 16);
            a0[2] += bf2f(v0.y & 0xffff); a0[3] += bf2f(v0.y >> 16);
            a0[4] += bf2f(v0.z & 0xffff); a0[5] += bf2f(v0.z >> 16);
            a0[6] += bf2f(v0.w & 0xffff); a0[7] += bf2f(v0.w >> 16);
        }
        #pragma unroll
        for (int q = 0; q < 8; ++q) a0[q] += a1[q];

        uint4 o;
        o.x = (unsigned)f2bf(a0[0]) | ((unsigned)f2bf(a0[1]) << 16);
        o.y = (unsigned)f2bf(a0[2]) | ((unsigned)f2bf(a0[3]) << 16);
        o.z = (unsigned)f2bf(a0[4]) | ((unsigned)f2bf(a0[5]) << 16);
        o.w = (unsigned)f2bf(a0[6]) | ((unsigned)f2bf(a0[7]) << 16);
        *(uint4*)&As[t][j * 8] = o;
    }
    __syncthreads();

    short8 a[2][4];
    #pragma unroll
    for (int rt = 0; rt < 2; ++rt)
        #pragma unroll
        for (int ks = 0; ks < 4; ++ks)
            a[rt][ks] = *(const short8*)&As[rt * 16 + m][ks * 32 + g * 8];

    f32x4 acc[2][2] = {};
    #pragma unroll
    for (int ks = 0; ks < 4; ++ks)
        #pragma unroll
        for (int rt = 0; rt < 2; ++rt)
            #pragma unroll
            for (int ct = 0; ct < 2; ++ct)
                acc[rt][ct] = __builtin_amdgcn_mfma_f32_16x16x32_bf16(
                    a[rt][ks], bfr[ct][ks], acc[rt][ct], 0, 0, 0);

    #pragma unroll
    for (int rt = 0; rt < 2; ++rt) {
        #pragma unroll
        for (int ct = 0; ct < 2; ++ct) {
            const int col = wid * 32 + ct * 16 + m;
            const float bv = ct ? bv1 : bv0;
            #pragma unroll
            for (int r = 0; r < 4; ++r) {
                const int row = b * 32 + rt * 16 + g * 4 + r;
                const size_t idx = (size_t)row * D_EMB + col;
                const float v = fmaxf(acc[rt][ct][r] + bv, 0.f);
                state[idx] = f2bf(bf2f(state[idx]) + v);
            }
        }
    }
}

// ---------------------------------------------------------------------------
// Pool (bf16 state): gs[batch[n]] += state[n]; batch sorted -> run accumulate
// ---------------------------------------------------------------------------
__global__ __launch_bounds__(256) void pool_kernel(
    const unsigned short* __restrict__ state, const int* __restrict__ batch,
    float* __restrict__ gs)
{
    const int lane = threadIdx.x & 63;
    const int grp  = threadIdx.x >> 6;
    const int n0 = blockIdx.x * 128 + grp * 32;
    const int c0 = lane * 2;

    float a0 = 0.f, a1 = 0.f;
    int cur = -1;
    for (int i = 0; i < 32; ++i) {
        const int n = n0 + i;
        if (n >= N_NODES) break;
        const int bb = batch[n];
        if (bb != cur) {
            if (cur >= 0) {
                unsafeAtomicAdd(&gs[cur * D_EMB + c0],     a0);
                unsafeAtomicAdd(&gs[cur * D_EMB + c0 + 1], a1);
            }
            cur = bb; a0 = 0.f; a1 = 0.f;
        }
        const unsigned u = *(const unsigned*)&state[(size_t)n * D_EMB + c0];
        a0 += bf2f(u & 0xffff);
        a1 += bf2f(u >> 16);
    }
    if (cur >= 0) {
        unsafeAtomicAdd(&gs[cur * D_EMB + c0],     a0);
        unsafeAtomicAdd(&gs[cur * D_EMB + c0 + 1], a1);
    }
}

__global__ __launch_bounds__(256) void out_kernel(
    const float* __restrict__ gs, const float* __restrict__ W,
    const float* __restrict__ bias, float* __restrict__ out)
{
    const int idx = blockIdx.x * 256 + threadIdx.x;
    const int g = idx >> 5;
    const int m = idx & 31;
    float acc = 0.f;
    #pragma unroll 8
    for (int k = 0; k < D_EMB; ++k)
        acc += gs[g * D_EMB + k] * W[k * M_OUT + m];
    out[idx] = acc + bias[m];
}

// ---------------------------------------------------------------------------
extern "C" void kernel_launch(void* const* d_in, const int* in_sizes, int n_in,
                              void* d_out, int out_size, void* d_ws, size_t ws_size,
                              hipStream_t stream)
{
    const float* x     = (const float*)d_in[0];
    const int*   eidx  = (const int*)d_in[1];
    const int*   batch = (const int*)d_in[2];
    const float* emb_W = (const float*)d_in[3];
    const float* emb_b = (const float*)d_in[4];
    const float* msg_W = (const float*)d_in[5];
    const float* msg_b = (const float*)d_in[6];
    const float* upd_W = (const float*)d_in[7];
    const float* upd_b = (const float*)d_in[8];
    const float* out_W = (const float*)d_in[9];
    const float* out_b = (const float*)d_in[10];
    float* out = (float*)d_out;

    const int* src = eidx;
    const int* dst = eidx + N_EDGES;

    // workspace carve
    char* p = (char*)d_ws;
    unsigned short* state = (unsigned short*)p;   p += (size_t)N_NODES * D_EMB * 2;
    unsigned short* msg   = (unsigned short*)p;   p += (size_t)N_NODES * D_EMB * 2;
    float* gs = (float*)p;                        p += (size_t)NUM_GRAPHS * D_EMB * 4;
    unsigned short* WTall = (unsigned short*)p;   p += (size_t)9 * D_EMB * D_EMB * 2;
    int* rp   = (int*)p;                          p += (size_t)(N_NODES + 1) * 4;
    int* deg  = (int*)p;                          p += (size_t)N_NODES * 4;
    int* pos  = (int*)p;                          p += (size_t)N_NODES * 4;
    int* chunkCnt = (int*)p;                      p += 64;
    int* partials = (int*)p;                      p += (size_t)128 * 4;
    int* esrc = (int*)p;                          p += (size_t)N_EDGES * 4;
    unsigned* chunkbuf = (unsigned*)p;            p += (size_t)NCHUNK * CHUNK_CAP * 4;

    const dim3 blk(256);
    const int edge_grid = N_EDGES / 256;   // 6250 exact

    // ---- weight prep + two-level XCD-confined CSR build ----
    prep_weights_kernel<<<9, blk, 0, stream>>>(emb_W, msg_W, upd_W, WTall);
    hipMemsetAsync(deg, 0, (size_t)N_NODES * sizeof(int), stream);
    hipMemsetAsync(chunkCnt, 0, 64, stream);
    partition_mp_kernel<<<edge_grid * NCHUNK, blk, 0, stream>>>(src, dst, chunkCnt, chunkbuf);
    histD_kernel<<<HISTD_BLOCKS, blk, 0, stream>>>(chunkbuf, chunkCnt, deg);
    scan_local_kernel<<<SCAN_NBLK, blk, 0, stream>>>(deg, rp, partials);
    scan_partials_kernel<<<1, 128, 0, stream>>>(partials);
    scan_fixup_kernel<<<(SCAN_NBLK * SCAN_ELEMS_PER_BLOCK) / 256, blk, 0, stream>>>(rp, partials, pos);
    fillD_kernel<<<FILLD_BLOCKS, blk, 0, stream>>>(chunkbuf, chunkCnt, pos, esrc);

    // ---- network ----
    gemm_loop_kernel<2, true><<<GEMM_BLOCKS, blk, 0, stream>>>(
        x, WTall, emb_b, state, nullptr);

    for (int r = 0; r < ROUNDS; ++r) {
        gemm_loop_kernel<0, false><<<GEMM_BLOCKS, blk, 0, stream>>>(
            state, WTall + (size_t)(1 + r) * D_EMB * D_EMB,
            msg_b + (size_t)r * D_EMB, nullptr, msg);
        fused_upd_kernel<<<N_TILES, blk, 0, stream>>>(
            msg, rp, esrc, WTall + (size_t)(5 + r) * D_EMB * D_EMB,
            upd_b + (size_t)r * D_EMB, state);
    }

    hipMemsetAsync(gs, 0, (size_t)NUM_GRAPHS * D_EMB * sizeof(float), stream);
    pool_kernel<<<(N_NODES + 127) / 128, blk, 0, stream>>>(state, batch, gs);
    out_kernel<<<(NUM_GRAPHS * M_OUT) / 256, blk, 0, stream>>>(gs, out_W, out_b, out);
}

// Round 9
// 599.899 us; speedup vs baseline: 4.8094x; 4.8094x over previous
//
#include <hip/hip_runtime.h>

#define N_NODES    100000
#define N_EDGES    1600000
#define D_EMB      128
#define ROUNDS     4
#define M_OUT      32
#define NUM_GRAPHS 512

#define N_TILES    (N_NODES / 32)        // 3125 GEMM tiles
#define GEMM_BLOCKS 1024

#define NPASS      8
#define PASS_RANGE (N_NODES / NPASS)     // 12500 dst nodes per pass

#define SCAN_ELEMS_PER_BLOCK 1024
#define SCAN_NBLK ((N_NODES + SCAN_ELEMS_PER_BLOCK - 1) / SCAN_ELEMS_PER_BLOCK)  // 98

typedef __attribute__((ext_vector_type(8))) short short8;
typedef __attribute__((ext_vector_type(4))) float f32x4;

static __device__ __forceinline__ unsigned short f2bf(float f) {
    union { float f; unsigned u; } v; v.f = f;
    unsigned u = v.u;
    unsigned r = (u + 0x7FFFu + ((u >> 16) & 1u)) >> 16;   // RNE
    return (unsigned short)r;
}
static __device__ __forceinline__ float bf2f(unsigned short h) {
    union { unsigned u; float f; } v; v.u = ((unsigned)h) << 16;
    return v.f;
}

// ---------------------------------------------------------------------------
// Weight prep: WTall[mi][n][k] = bf16( W_mi[k][n] )
// ---------------------------------------------------------------------------
__global__ __launch_bounds__(256) void prep_weights_kernel(
    const float* __restrict__ emb_W, const float* __restrict__ msg_W,
    const float* __restrict__ upd_W, unsigned short* __restrict__ WTall)
{
    const int mi = blockIdx.x;
    const float* W = (mi == 0) ? emb_W
                   : (mi <= 4) ? msg_W + (size_t)(mi - 1) * D_EMB * D_EMB
                               : upd_W + (size_t)(mi - 5) * D_EMB * D_EMB;
    unsigned short* WT = WTall + (size_t)mi * D_EMB * D_EMB;
    for (int idx = threadIdx.x; idx < D_EMB * D_EMB; idx += 256) {
        const int n = idx >> 7, k = idx & 127;
        WT[idx] = f2bf(W[k * D_EMB + n]);
    }
}

// ---------------------------------------------------------------------------
// Looped bf16 MFMA GEMM (emb + msg rounds). Double-buffered A staging,
// B fragments loaded once per block.
// MODE 0: outb = bf16(relu(AW+b))     (msg)
// MODE 2: state = bf16(relu(AW+b))    (embed, A is fp32 x)
// ---------------------------------------------------------------------------
template<int MODE, bool AF32>
__global__ __launch_bounds__(256) void gemm_loop_kernel(
    const void* __restrict__ Aptr, const unsigned short* __restrict__ WT,
    const float* __restrict__ bias, unsigned short* __restrict__ state,
    unsigned short* __restrict__ outb)
{
    __shared__ unsigned short As[2][32][136];   // +8 pad: row stride 272 B

    const int tid  = threadIdx.x;
    const int lane = tid & 63;
    const int w    = tid >> 6;
    const int m    = lane & 15;
    const int g    = lane >> 4;

    short8 bfr[2][4];
    #pragma unroll
    for (int ct = 0; ct < 2; ++ct) {
        const int n = w * 32 + ct * 16 + m;
        #pragma unroll
        for (int ks = 0; ks < 4; ++ks)
            bfr[ct][ks] = *(const short8*)&WT[n * D_EMB + ks * 32 + g * 8];
    }
    const float bv0 = bias[w * 32 + m];
    const float bv1 = bias[w * 32 + 16 + m];

    int tile = blockIdx.x;

    if (AF32) {
        const float4* A4 = (const float4*)Aptr;
        #pragma unroll
        for (int i = 0; i < 4; ++i) {
            const int ch = tid + (i << 8);
            const float4 f = A4[(size_t)tile * 1024 + ch];
            ushort4 h; h.x = f2bf(f.x); h.y = f2bf(f.y); h.z = f2bf(f.z); h.w = f2bf(f.w);
            *(ushort4*)&As[0][ch >> 5][(ch & 31) << 2] = h;
        }
    } else {
        const uint4* A2 = (const uint4*)Aptr;
        #pragma unroll
        for (int i = 0; i < 2; ++i) {
            const int ch = tid + (i << 8);
            const uint4 v = A2[(size_t)tile * 512 + ch];
            *(uint4*)&As[0][ch >> 4][(ch & 15) << 3] = v;
        }
    }
    __syncthreads();

    int cur = 0;
    while (true) {
        const int next = tile + GEMM_BLOCKS;
        const bool have = next < N_TILES;

        float4 rgf[4]; uint4 rgu[2];
        if (have) {
            if (AF32) {
                const float4* A4 = (const float4*)Aptr;
                #pragma unroll
                for (int i = 0; i < 4; ++i)
                    rgf[i] = A4[(size_t)next * 1024 + tid + (i << 8)];
            } else {
                const uint4* A2 = (const uint4*)Aptr;
                #pragma unroll
                for (int i = 0; i < 2; ++i)
                    rgu[i] = A2[(size_t)next * 512 + tid + (i << 8)];
            }
        }

        short8 a[2][4];
        #pragma unroll
        for (int rt = 0; rt < 2; ++rt)
            #pragma unroll
            for (int ks = 0; ks < 4; ++ks)
                a[rt][ks] = *(const short8*)&As[cur][rt * 16 + m][ks * 32 + g * 8];

        f32x4 acc[2][2] = {};
        #pragma unroll
        for (int ks = 0; ks < 4; ++ks)
            #pragma unroll
            for (int rt = 0; rt < 2; ++rt)
                #pragma unroll
                for (int ct = 0; ct < 2; ++ct)
                    acc[rt][ct] = __builtin_amdgcn_mfma_f32_16x16x32_bf16(
                        a[rt][ks], bfr[ct][ks], acc[rt][ct], 0, 0, 0);

        if (have) {
            if (AF32) {
                #pragma unroll
                for (int i = 0; i < 4; ++i) {
                    const int ch = tid + (i << 8);
                    ushort4 h;
                    h.x = f2bf(rgf[i].x); h.y = f2bf(rgf[i].y);
                    h.z = f2bf(rgf[i].z); h.w = f2bf(rgf[i].w);
                    *(ushort4*)&As[cur ^ 1][ch >> 5][(ch & 31) << 2] = h;
                }
            } else {
                #pragma unroll
                for (int i = 0; i < 2; ++i) {
                    const int ch = tid + (i << 8);
                    *(uint4*)&As[cur ^ 1][ch >> 4][(ch & 15) << 3] = rgu[i];
                }
            }
        }

        #pragma unroll
        for (int rt = 0; rt < 2; ++rt) {
            #pragma unroll
            for (int ct = 0; ct < 2; ++ct) {
                const int col = w * 32 + ct * 16 + m;
                const float bv = ct ? bv1 : bv0;
                #pragma unroll
                for (int r = 0; r < 4; ++r) {
                    const int row = tile * 32 + rt * 16 + g * 4 + r;
                    const size_t idx = (size_t)row * D_EMB + col;
                    const float v = fmaxf(acc[rt][ct][r] + bv, 0.f);
                    if (MODE == 0) outb[idx] = f2bf(v);
                    else           state[idx] = f2bf(v);
                }
            }
        }

        if (!have) break;
        __syncthreads();
        cur ^= 1;
        tile = next;
    }
}

// ---------------------------------------------------------------------------
// CSR build (R4-proven): XCD-confined multipass hist + fill on PER-NODE
// counters (100K addresses -> no same-address atomic chains).
// ---------------------------------------------------------------------------
__global__ __launch_bounds__(256) void hist_mp_kernel(
    const int* __restrict__ dst, int* __restrict__ deg)
{
    const int p = blockIdx.x & 7;
    const int e = (blockIdx.x >> 3) * 256 + threadIdx.x;
    const int d = dst[e];
    if ((unsigned)(d - p * PASS_RANGE) < (unsigned)PASS_RANGE)
        atomicAdd(&deg[d], 1);
}

__global__ __launch_bounds__(256) void scan_local_kernel(
    const int* __restrict__ deg, int* __restrict__ rp, int* __restrict__ partials)
{
    __shared__ int sm[256];
    const int tid  = threadIdx.x;
    const int base = blockIdx.x * SCAN_ELEMS_PER_BLOCK + tid * 4;

    int v0 = (base + 0 < N_NODES) ? deg[base + 0] : 0;
    int v1 = (base + 1 < N_NODES) ? deg[base + 1] : 0;
    int v2 = (base + 2 < N_NODES) ? deg[base + 2] : 0;
    int v3 = (base + 3 < N_NODES) ? deg[base + 3] : 0;
    const int tot = v0 + v1 + v2 + v3;

    sm[tid] = tot;
    __syncthreads();
    #pragma unroll
    for (int off = 1; off < 256; off <<= 1) {
        const int x = (tid >= off) ? sm[tid - off] : 0;
        __syncthreads();
        sm[tid] += x;
        __syncthreads();
    }
    const int bex = sm[tid] - tot;

    if (base + 0 < N_NODES) rp[base + 0] = bex;
    if (base + 1 < N_NODES) rp[base + 1] = bex + v0;
    if (base + 2 < N_NODES) rp[base + 2] = bex + v0 + v1;
    if (base + 3 < N_NODES) rp[base + 3] = bex + v0 + v1 + v2;
    if (tid == 255) partials[blockIdx.x] = sm[255];
}

__global__ __launch_bounds__(128) void scan_partials_kernel(int* __restrict__ partials)
{
    __shared__ int sm[128];
    const int tid = threadIdx.x;
    const int v = (tid < SCAN_NBLK) ? partials[tid] : 0;
    sm[tid] = v;
    __syncthreads();
    #pragma unroll
    for (int off = 1; off < 128; off <<= 1) {
        const int x = (tid >= off) ? sm[tid - off] : 0;
        __syncthreads();
        sm[tid] += x;
        __syncthreads();
    }
    if (tid < SCAN_NBLK) partials[tid] = sm[tid] - v;
}

__global__ __launch_bounds__(256) void scan_fixup_kernel(
    int* __restrict__ rp, const int* __restrict__ partials, int* __restrict__ pos)
{
    const int i = blockIdx.x * 256 + threadIdx.x;
    if (i < N_NODES) {
        const int v = rp[i] + partials[i >> 10];
        rp[i] = v;
        pos[i] = v;
    }
    if (i == 0) rp[N_NODES] = N_EDGES;
}

__global__ __launch_bounds__(256) void fill_mp_kernel(
    const int* __restrict__ src, const int* __restrict__ dst,
    int* __restrict__ pos, int* __restrict__ esrc)
{
    const int p = blockIdx.x & 7;
    const int e = (blockIdx.x >> 3) * 256 + threadIdx.x;
    const int d = dst[e];
    if ((unsigned)(d - p * PASS_RANGE) < (unsigned)PASS_RANGE) {
        const int idx = atomicAdd(&pos[d], 1);
        esrc[idx] = src[e];
    }
}

// ---------------------------------------------------------------------------
// Fused gather + update-GEMM. Block b owns dst nodes [32b, 32b+32).
// Gather: 16 lane-groups pop nodes off an LDS work queue (load balance);
// fp32 register accumulation, 4 edges in flight; one ds_write_b128 per
// (node, 16B-chunk). Then MFMA with upd W and in-place bf16 residual.
// ---------------------------------------------------------------------------
__global__ __launch_bounds__(256) void fused_upd_kernel(
    const unsigned short* __restrict__ msg, const int* __restrict__ rp,
    const int* __restrict__ esrc, const unsigned short* __restrict__ WT,
    const float* __restrict__ bias, unsigned short* __restrict__ state)
{
    __shared__ unsigned short As[32][136];    // 8.5 KB, +8 pad
    __shared__ int wq;

    const int tid  = threadIdx.x;
    const int lane = tid & 63;
    const int wid  = tid >> 6;
    const int m    = lane & 15;
    const int g    = lane >> 4;
    const int b    = blockIdx.x;
    const int j    = tid & 15;       // 16B column chunk within row

    if (tid == 0) wq = 0;

    short8 bfr[2][4];
    #pragma unroll
    for (int ct = 0; ct < 2; ++ct) {
        const int n = wid * 32 + ct * 16 + m;
        #pragma unroll
        for (int ks = 0; ks < 4; ++ks)
            bfr[ct][ks] = *(const short8*)&WT[n * D_EMB + ks * 32 + g * 8];
    }
    const float bv0 = bias[wid * 32 + m];
    const float bv1 = bias[wid * 32 + 16 + m];

    __syncthreads();   // wq ready

    const uint4* m4 = (const uint4*)msg;   // row = 16 uint4

    while (true) {
        int t = 0;
        if (j == 0) t = atomicAdd(&wq, 1);
        t = __shfl(t, lane & 48, 64);      // broadcast from 16-group leader
        if (t >= 32) break;

        const int n = b * 32 + t;
        const int beg = rp[n];
        const int end = rp[n + 1];

        float a0[8] = {0,0,0,0,0,0,0,0};
        float a1[8] = {0,0,0,0,0,0,0,0};
        int i = beg;
        for (; i + 3 < end; i += 4) {
            const uint4 v0 = m4[(size_t)esrc[i]     * 16 + j];
            const uint4 v1 = m4[(size_t)esrc[i + 1] * 16 + j];
            const uint4 v2 = m4[(size_t)esrc[i + 2] * 16 + j];
            const uint4 v3 = m4[(size_t)esrc[i + 3] * 16 + j];
            a0[0] += bf2f(v0.x & 0xffff); a0[1] += bf2f(v0.x >> 16);
            a0[2] += bf2f(v0.y & 0xffff); a0[3] += bf2f(v0.y >> 16);
            a0[4] += bf2f(v0.z & 0xffff); a0[5] += bf2f(v0.z >> 16);
            a0[6] += bf2f(v0.w & 0xffff); a0[7] += bf2f(v0.w >> 16);
            a1[0] += bf2f(v1.x & 0xffff); a1[1] += bf2f(v1.x >> 16);
            a1[2] += bf2f(v1.y & 0xffff); a1[3] += bf2f(v1.y >> 16);
            a1[4] += bf2f(v1.z & 0xffff); a1[5] += bf2f(v1.z >> 16);
            a1[6] += bf2f(v1.w & 0xffff); a1[7] += bf2f(v1.w >> 16);
            a0[0] += bf2f(v2.x & 0xffff); a0[1] += bf2f(v2.x >> 16);
            a0[2] += bf2f(v2.y & 0xffff); a0[3] += bf2f(v2.y >> 16);
            a0[4] += bf2f(v2.z & 0xffff); a0[5] += bf2f(v2.z >> 16);
            a0[6] += bf2f(v2.w & 0xffff); a0[7] += bf2f(v2.w >> 16);
            a1[0] += bf2f(v3.x & 0xffff); a1[1] += bf2f(v3.x >> 16);
            a1[2] += bf2f(v3.y & 0xffff); a1[3] += bf2f(v3.y >> 16);
            a1[4] += bf2f(v3.z & 0xffff); a1[5] += bf2f(v3.z >> 16);
            a1[6] += bf2f(v3.w & 0xffff); a1[7] += bf2f(v3.w >> 16);
        }
        for (; i < end; ++i) {
            const uint4 v0 = m4[(size_t)esrc[i] * 16 + j];
            a0[0] += bf2f(v0.x & 0xffff); a0[1] += bf2f(v0.x >> 16);
            a0[2] += bf2f(v0.y & 0xffff); a0[3] += bf2f(v0.y >> 16);
            a0[4] += bf2f(v0.z & 0xffff); a0[5] += bf2f(v0.z >> 16);
            a0[6] += bf2f(v0.w & 0xffff); a0[7] += bf2f(v0.w >> 16);
        }
        #pragma unroll
        for (int q = 0; q < 8; ++q) a0[q] += a1[q];

        uint4 o;
        o.x = (unsigned)f2bf(a0[0]) | ((unsigned)f2bf(a0[1]) << 16);
        o.y = (unsigned)f2bf(a0[2]) | ((unsigned)f2bf(a0[3]) << 16);
        o.z = (unsigned)f2bf(a0[4]) | ((unsigned)f2bf(a0[5]) << 16);
        o.w = (unsigned)f2bf(a0[6]) | ((unsigned)f2bf(a0[7]) << 16);
        *(uint4*)&As[t][j * 8] = o;
    }
    __syncthreads();

    short8 a[2][4];
    #pragma unroll
    for (int rt = 0; rt < 2; ++rt)
        #pragma unroll
        for (int ks = 0; ks < 4; ++ks)
            a[rt][ks] = *(const short8*)&As[rt * 16 + m][ks * 32 + g * 8];

    f32x4 acc[2][2] = {};
    #pragma unroll
    for (int ks = 0; ks < 4; ++ks)
        #pragma unroll
        for (int rt = 0; rt < 2; ++rt)
            #pragma unroll
            for (int ct = 0; ct < 2; ++ct)
                acc[rt][ct] = __builtin_amdgcn_mfma_f32_16x16x32_bf16(
                    a[rt][ks], bfr[ct][ks], acc[rt][ct], 0, 0, 0);

    #pragma unroll
    for (int rt = 0; rt < 2; ++rt) {
        #pragma unroll
        for (int ct = 0; ct < 2; ++ct) {
            const int col = wid * 32 + ct * 16 + m;
            const float bv = ct ? bv1 : bv0;
            #pragma unroll
            for (int r = 0; r < 4; ++r) {
                const int row = b * 32 + rt * 16 + g * 4 + r;
                const size_t idx = (size_t)row * D_EMB + col;
                const float v = fmaxf(acc[rt][ct][r] + bv, 0.f);
                state[idx] = f2bf(bf2f(state[idx]) + v);
            }
        }
    }
}

// ---------------------------------------------------------------------------
// Pool (bf16 state): gs[batch[n]] += state[n]; batch sorted -> run accumulate
// ---------------------------------------------------------------------------
__global__ __launch_bounds__(256) void pool_kernel(
    const unsigned short* __restrict__ state, const int* __restrict__ batch,
    float* __restrict__ gs)
{
    const int lane = threadIdx.x & 63;
    const int grp  = threadIdx.x >> 6;
    const int n0 = blockIdx.x * 128 + grp * 32;
    const int c0 = lane * 2;

    float a0 = 0.f, a1 = 0.f;
    int cur = -1;
    for (int i = 0; i < 32; ++i) {
        const int n = n0 + i;
        if (n >= N_NODES) break;
        const int bb = batch[n];
        if (bb != cur) {
            if (cur >= 0) {
                unsafeAtomicAdd(&gs[cur * D_EMB + c0],     a0);
                unsafeAtomicAdd(&gs[cur * D_EMB + c0 + 1], a1);
            }
            cur = bb; a0 = 0.f; a1 = 0.f;
        }
        const unsigned u = *(const unsigned*)&state[(size_t)n * D_EMB + c0];
        a0 += bf2f(u & 0xffff);
        a1 += bf2f(u >> 16);
    }
    if (cur >= 0) {
        unsafeAtomicAdd(&gs[cur * D_EMB + c0],     a0);
        unsafeAtomicAdd(&gs[cur * D_EMB + c0 + 1], a1);
    }
}

__global__ __launch_bounds__(256) void out_kernel(
    const float* __restrict__ gs, const float* __restrict__ W,
    const float* __restrict__ bias, float* __restrict__ out)
{
    const int idx = blockIdx.x * 256 + threadIdx.x;
    const int g = idx >> 5;
    const int m = idx & 31;
    float acc = 0.f;
    #pragma unroll 8
    for (int k = 0; k < D_EMB; ++k)
        acc += gs[g * D_EMB + k] * W[k * M_OUT + m];
    out[idx] = acc + bias[m];
}

// ---------------------------------------------------------------------------
extern "C" void kernel_launch(void* const* d_in, const int* in_sizes, int n_in,
                              void* d_out, int out_size, void* d_ws, size_t ws_size,
                              hipStream_t stream)
{
    const float* x     = (const float*)d_in[0];
    const int*   eidx  = (const int*)d_in[1];
    const int*   batch = (const int*)d_in[2];
    const float* emb_W = (const float*)d_in[3];
    const float* emb_b = (const float*)d_in[4];
    const float* msg_W = (const float*)d_in[5];
    const float* msg_b = (const float*)d_in[6];
    const float* upd_W = (const float*)d_in[7];
    const float* upd_b = (const float*)d_in[8];
    const float* out_W = (const float*)d_in[9];
    const float* out_b = (const float*)d_in[10];
    float* out = (float*)d_out;

    const int* src = eidx;
    const int* dst = eidx + N_EDGES;

    // workspace carve
    char* p = (char*)d_ws;
    unsigned short* state = (unsigned short*)p;   p += (size_t)N_NODES * D_EMB * 2;
    unsigned short* msg   = (unsigned short*)p;   p += (size_t)N_NODES * D_EMB * 2;
    float* gs = (float*)p;                        p += (size_t)NUM_GRAPHS * D_EMB * 4;
    unsigned short* WTall = (unsigned short*)p;   p += (size_t)9 * D_EMB * D_EMB * 2;
    int* rp   = (int*)p;                          p += (size_t)(N_NODES + 1) * 4;
    int* deg  = (int*)p;                          p += (size_t)N_NODES * 4;
    int* pos  = (int*)p;                          p += (size_t)N_NODES * 4;
    int* partials = (int*)p;                      p += (size_t)128 * 4;
    int* esrc = (int*)p;                          p += (size_t)N_EDGES * 4;

    const dim3 blk(256);
    const int mp_grid = (N_EDGES / 256) * NPASS;   // 50000

    // ---- weight prep + CSR build (R4-proven structure) ----
    prep_weights_kernel<<<9, blk, 0, stream>>>(emb_W, msg_W, upd_W, WTall);
    hipMemsetAsync(deg, 0, (size_t)N_NODES * sizeof(int), stream);
    hist_mp_kernel<<<mp_grid, blk, 0, stream>>>(dst, deg);
    scan_local_kernel<<<SCAN_NBLK, blk, 0, stream>>>(deg, rp, partials);
    scan_partials_kernel<<<1, 128, 0, stream>>>(partials);
    scan_fixup_kernel<<<(SCAN_NBLK * SCAN_ELEMS_PER_BLOCK) / 256, blk, 0, stream>>>(rp, partials, pos);
    fill_mp_kernel<<<mp_grid, blk, 0, stream>>>(src, dst, pos, esrc);

    // ---- network ----
    gemm_loop_kernel<2, true><<<GEMM_BLOCKS, blk, 0, stream>>>(
        x, WTall, emb_b, state, nullptr);

    for (int r = 0; r < ROUNDS; ++r) {
        gemm_loop_kernel<0, false><<<GEMM_BLOCKS, blk, 0, stream>>>(
            state, WTall + (size_t)(1 + r) * D_EMB * D_EMB,
            msg_b + (size_t)r * D_EMB, nullptr, msg);
        fused_upd_kernel<<<N_TILES, blk, 0, stream>>>(
            msg, rp, esrc, WTall + (size_t)(5 + r) * D_EMB * D_EMB,
            upd_b + (size_t)r * D_EMB, state);
    }

    hipMemsetAsync(gs, 0, (size_t)NUM_GRAPHS * D_EMB * sizeof(float), stream);
    pool_kernel<<<(N_NODES + 127) / 128, blk, 0, stream>>>(state, batch, gs);
    out_kernel<<<(NUM_GRAPHS * M_OUT) / 256, blk, 0, stream>>>(gs, out_W, out_b, out);
}